// Round 8
// baseline (111.796 us; speedup 1.0000x reference)
//
#include <hip/hip_runtime.h>
#include <hip/hip_bf16.h>

#define B_ 8
#define N_ 512
#define F_ 128
#define H_ 4
#define U_ 32
#define LEAKY_ALPHA 0.2f
#define PS 520     // pbf row stride (bf16 elems)
#define TS 133     // d^T row stride (floats): odd mod 32 -> lane-consecutive
                   // b32 column reads are conflict-free

typedef __attribute__((ext_vector_type(8))) short short8;
typedef __attribute__((ext_vector_type(4))) float f32x4;

static __device__ __forceinline__ short f2bf_s(float x) {
    __hip_bfloat16 hv = __float2bfloat16(x);
    return *reinterpret_cast<short*>(&hv);
}
static __device__ __forceinline__ float bf2f_s(short v) {
    return __uint_as_float(((unsigned)(unsigned short)v) << 16);
}

// ---------------------------------------------------------------------------
// Kernel 1: projections (unchanged).
//   hsrc  = x@Wsrc (f32)            [bh][n][u]
//   hsrcT = bf16(x@Wsrc)^T          [bh*32+u][n]  (MFMA B-frag layout)
//   hdstN = -(x@Wdst) (f32)         [bh][n][u]
//   Drow[j] = sum_u a_u d_ju ; ascaled = 0.8*a
// score(i,j) ~ D_j + sum_u (0.8 a_u) max(s_iu, -d_ju)  (0.2*A_i dropped;
// softmax shift-invariant).
// ---------------------------------------------------------------------------
__global__ __launch_bounds__(256) void proj_kernel(
    const float* __restrict__ x, const float* __restrict__ Wsrc,
    const float* __restrict__ Wdst, const float* __restrict__ a,
    float* __restrict__ hsrc, float* __restrict__ hdstN,
    float* __restrict__ Drow, float* __restrict__ ascaled,
    short* __restrict__ hsrcT)
{
    __shared__ float4 xlds[8 * 32];
    const int t  = threadIdx.x;
    const int r0 = blockIdx.x * 8;

    const float4* xg = (const float4*)x + (size_t)r0 * 32;
    xlds[t] = xg[t];
    __syncthreads();

    const int u     = t & 31;
    const int h     = (t >> 5) & 3;
    const int which = t >> 7;
    const float* W  = (which ? Wdst : Wsrc) + h * (F_ * U_) + u;

    float acc[8];
#pragma unroll
    for (int r = 0; r < 8; ++r) acc[r] = 0.f;

#pragma unroll 2
    for (int fc = 0; fc < 32; ++fc) {
        const float w0 = W[(4 * fc + 0) * U_];
        const float w1 = W[(4 * fc + 1) * U_];
        const float w2 = W[(4 * fc + 2) * U_];
        const float w3 = W[(4 * fc + 3) * U_];
#pragma unroll
        for (int r = 0; r < 8; ++r) {
            const float4 xv = xlds[r * 32 + fc];
            float s = acc[r];
            s = fmaf(xv.x, w0, s);
            s = fmaf(xv.y, w1, s);
            s = fmaf(xv.z, w2, s);
            s = fmaf(xv.w, w3, s);
            acc[r] = s;
        }
    }

    const float av = a[h * U_ + u];
    if (which == 1 && blockIdx.x == 0)
        ascaled[h * U_ + u] = (1.f - LEAKY_ALPHA) * av;

    const int b  = r0 >> 9;
    const int n0 = r0 & (N_ - 1);

    if (which == 0) {
        short8 pk;
#pragma unroll
        for (int r = 0; r < 8; ++r) {
            const size_t base = ((size_t)((b * H_ + h) * N_ + n0 + r) << 5) + u;
            hsrc[base] = acc[r];
            pk[r] = f2bf_s(acc[r]);
        }
        *(short8*)&hsrcT[((size_t)((b * H_ + h) * U_) + u) * N_ + n0] = pk;
    } else {
#pragma unroll
        for (int r = 0; r < 8; ++r) {
            const size_t base = ((size_t)((b * H_ + h) * N_ + n0 + r) << 5) + u;
            hdstN[base] = -acc[r];
            float v = acc[r] * av;
            v += __shfl_xor(v, 1);
            v += __shfl_xor(v, 2);
            v += __shfl_xor(v, 4);
            v += __shfl_xor(v, 8);
            v += __shfl_xor(v, 16);
            if (u == 0) Drow[(b * H_ + h) * N_ + n0 + r] = v;
        }
    }
}

// ---------------------------------------------------------------------------
// Kernel 2: attention. i-register-blocked phase A: lane = (jl = t&127,
// i-half = wave>>1 [readfirstlane -> provably uniform]); lane holds one full
// d-row in 32 VGPRs (filled from a TRANSPOSED LDS tile [u][j], stride 133:
// conflict-free b32 column reads) and computes 8 i's against it. s-rows are
// wave-uniform -> s_load (scalar pipe); a' in VGPRs. 8x fewer LDS read
// instrs than R7. Phase C: MFMA p @ srcT, B-frags direct from global hsrcT.
// Block = 256 thr = 4 waves, tile = 16 i; grid = 32 bh x 32 tiles.
// ---------------------------------------------------------------------------
__global__ __launch_bounds__(256, 4) void attn_kernel(
    const float* __restrict__ hsrc, const float* __restrict__ hdstN,
    const float* __restrict__ Drow, const float* __restrict__ ascaled,
    const short* __restrict__ hsrcT, float* __restrict__ out)
{
    __shared__ float dt[32 * TS];                 // 17.0 KB d^T tile [u][j]
    __shared__ __align__(16) short pbf[16 * PS];  // 16.6 KB p bf16 [i][j]
    __shared__ f32x4 scr[4][64];                  // 4 KB K-partials
    __shared__ float lpart[4][8];                 // per-wave l partials
    __shared__ float lfin[16];                    // 1/l per i

    const int t    = threadIdx.x;
    const int L    = t & 63;
    const int w    = __builtin_amdgcn_readfirstlane(t >> 6);
    const int p8   = w >> 1;                      // i-half, wave-uniform
    const int jl   = t & 127;                     // row within 128-j tile
    const int tile = blockIdx.x & 31;
    const int bh   = blockIdx.x >> 5;
    const int h    = bh & 3;
    const int b    = bh >> 2;
    const size_t bhN = (size_t)bh * N_;
    const int ig0  = tile * 16;

    // 0.8*a in VGPRs (per-lane copy; pairs with SGPR s in max/fma)
    float4 av4[8];
    {
        const float4* ag = (const float4*)(ascaled + h * U_);
#pragma unroll
        for (int q = 0; q < 8; ++q) av4[q] = ag[q];
    }

    const float4* dg = (const float4*)(hdstN + (bhN << 5));  // 1024 f4/tile
    const float* srow_base = hsrc + ((bhN + ig0 + p8 * 8) << 5);  // uniform

    float lp[8];
#pragma unroll
    for (int k = 0; k < 8; ++k) lp[k] = 0.f;

    // prefetch tile 0
    float4 pre0 = dg[t];
    float4 pre1 = dg[t + 256];
    float4 pre2 = dg[t + 512];
    float4 pre3 = dg[t + 768];

    for (int jt = 0; jt < 4; ++jt) {
        __syncthreads();
        {   // commit prefetched tile to LDS, transposed [u][j]
#define COMMIT(pre, qq)                                          \
            {                                                    \
                const int idx = t + 256 * (qq);                  \
                const int j = idx >> 3, u4 = idx & 7;            \
                dt[(4 * u4 + 0) * TS + j] = pre.x;               \
                dt[(4 * u4 + 1) * TS + j] = pre.y;               \
                dt[(4 * u4 + 2) * TS + j] = pre.z;               \
                dt[(4 * u4 + 3) * TS + j] = pre.w;               \
            }
            COMMIT(pre0, 0) COMMIT(pre1, 1) COMMIT(pre2, 2) COMMIT(pre3, 3)
#undef COMMIT
        }
        __syncthreads();
        if (jt < 3) {   // prefetch next tile (latency hidden by compute)
            const float4* dn = dg + (jt + 1) * 1024;
            pre0 = dn[t];
            pre1 = dn[t + 256];
            pre2 = dn[t + 512];
            pre3 = dn[t + 768];
        }

        // fill this lane's d-row into registers: conflict-free b32 column
        float d[32];
#pragma unroll
        for (int u = 0; u < 32; ++u) d[u] = dt[u * TS + jl];

        const float Dj = Drow[bhN + jt * 128 + jl];

#pragma unroll
        for (int ii = 0; ii < 8; ++ii) {
            const float* srow = srow_base + (ii << 5);   // wave-uniform
            float acA = 0.f, acB = 0.f;
#pragma unroll
            for (int q = 0; q < 8; ++q) {
                acA = fmaf(av4[q].x, fmaxf(srow[4 * q + 0], d[4 * q + 0]), acA);
                acB = fmaf(av4[q].y, fmaxf(srow[4 * q + 1], d[4 * q + 1]), acB);
                acA = fmaf(av4[q].z, fmaxf(srow[4 * q + 2], d[4 * q + 2]), acA);
                acB = fmaf(av4[q].w, fmaxf(srow[4 * q + 3], d[4 * q + 3]), acB);
            }
            const float e  = __expf(Dj + acA + acB);
            const short qv = f2bf_s(e);
            pbf[(p8 * 8 + ii) * PS + jt * 128 + jl] = qv;
            lp[ii] += bf2f_s(qv);
        }
    }

    // reduce lp[8] across the 64 lanes of this wave
#pragma unroll
    for (int k = 0; k < 8; ++k) {
        float v = lp[k];
        v += __shfl_xor(v, 1);
        v += __shfl_xor(v, 2);
        v += __shfl_xor(v, 4);
        v += __shfl_xor(v, 8);
        v += __shfl_xor(v, 16);
        v += __shfl_xor(v, 32);
        lp[k] = v;
    }
    if (L == 0) {
#pragma unroll
        for (int k = 0; k < 8; ++k) lpart[w][k] = lp[k];
    }
    __syncthreads();

    if (t < 16) {   // l_i = lpart[2p][ii] + lpart[2p+1][ii]
        const int ii = t & 7, ph = t >> 3;
        lfin[t] = __builtin_amdgcn_rcpf(lpart[2 * ph][ii] + lpart[2 * ph + 1][ii]);
    }

    // ---- Phase C: MFMA  out = p @ src ----
    const int m  = L & 15;
    const int kq = L >> 4;
    const int nt = w & 1;
    const int ks = w >> 1;
    const short* Ap = pbf + m * PS + ks * 256 + kq * 8;
    const short* Bp = hsrcT + ((size_t)bh * U_ + nt * 16 + m) * N_ + ks * 256 + kq * 8;

    f32x4 acc = {0.f, 0.f, 0.f, 0.f};
#pragma unroll
    for (int st = 0; st < 8; ++st) {
        const short8 af = *(const short8*)(Ap + st * 32);
        const short8 bf = *(const short8*)(Bp + st * 32);
        acc = __builtin_amdgcn_mfma_f32_16x16x32_bf16(af, bf, acc, 0, 0, 0);
    }
    scr[w][L] = acc;
    __syncthreads();

    if (w < 2) {                               // wave w reduces ntile=w
        const f32x4 q0 = scr[w][L];
        const f32x4 q1 = scr[w + 2][L];
#pragma unroll
        for (int r = 0; r < 4; ++r) {
            const int il = kq * 4 + r;         // C/D: row=(lane>>4)*4+reg
            out[((size_t)(b * N_ + ig0 + il)) * (H_ * U_) + h * U_ + w * 16 + m]
                = (q0[r] + q1[r]) * lfin[il];
        }
    }
}

// ---------------------------------------------------------------------------
extern "C" void kernel_launch(void* const* d_in, const int* in_sizes, int n_in,
                              void* d_out, int out_size, void* d_ws, size_t ws_size,
                              hipStream_t stream) {
    const float* x    = (const float*)d_in[0];
    const float* Wsrc = (const float*)d_in[1];
    const float* Wdst = (const float*)d_in[2];
    const float* a    = (const float*)d_in[3];

    float* ws      = (float*)d_ws;
    float* hsrc    = ws;
    float* hdstN   = hsrc + (size_t)B_ * H_ * N_ * U_;
    float* Drow    = hdstN + (size_t)B_ * H_ * N_ * U_;
    float* ascaled = Drow + (size_t)B_ * H_ * N_;
    short* hsrcT   = (short*)(ascaled + H_ * U_);

    proj_kernel<<<(B_ * N_) / 8, 256, 0, stream>>>(x, Wsrc, Wdst, a,
                                                   hsrc, hdstN, Drow, ascaled,
                                                   hsrcT);
    attn_kernel<<<B_ * H_ * (N_ / 16), 256, 0, stream>>>(hsrc, hdstN, Drow,
                                                         ascaled, hsrcT,
                                                         (float*)d_out);
}

// Round 9
// 98.116 us; speedup vs baseline: 1.1394x; 1.1394x over previous
//
#include <hip/hip_runtime.h>
#include <hip/hip_bf16.h>

#define B_ 8
#define N_ 512
#define F_ 128
#define H_ 4
#define U_ 32
#define LEAKY_ALPHA 0.2f
#define PS 520     // pbf row stride (bf16 elems); 1040 B row -> 16B-aligned

typedef __attribute__((ext_vector_type(8))) short short8;
typedef __attribute__((ext_vector_type(4))) float f32x4;

static __device__ __forceinline__ short f2bf_s(float x) {
    __hip_bfloat16 hv = __float2bfloat16(x);
    return *reinterpret_cast<short*>(&hv);
}
static __device__ __forceinline__ float bf2f_s(short v) {
    return __uint_as_float(((unsigned)(unsigned short)v) << 16);
}

// ---------------------------------------------------------------------------
// Kernel 1: projections.
//   hsrc   = x@Wsrc (f32)           [bh][n][u]   (uniform s-row scalar loads)
//   hsrcT  = bf16(x@Wsrc)^T         [bh*32+u][n] (MFMA B-frag layout)
//   hdstNT = -(x@Wdst) (f32)^T      [bh*32+u][j] (coalesced per-lane d-rows)
//   Drow[j] = sum_u a_u d_ju ; ascaled = 0.8*a
// score(i,j) ~ D_j + sum_u (0.8 a_u) max(s_iu, -d_ju)  (0.2*A_i dropped;
// softmax shift-invariant).
// ---------------------------------------------------------------------------
__global__ __launch_bounds__(256) void proj_kernel(
    const float* __restrict__ x, const float* __restrict__ Wsrc,
    const float* __restrict__ Wdst, const float* __restrict__ a,
    float* __restrict__ hsrc, float* __restrict__ hdstNT,
    float* __restrict__ Drow, float* __restrict__ ascaled,
    short* __restrict__ hsrcT)
{
    __shared__ float4 xlds[8 * 32];
    const int t  = threadIdx.x;
    const int r0 = blockIdx.x * 8;

    const float4* xg = (const float4*)x + (size_t)r0 * 32;
    xlds[t] = xg[t];
    __syncthreads();

    const int u     = t & 31;
    const int h     = (t >> 5) & 3;
    const int which = t >> 7;
    const float* W  = (which ? Wdst : Wsrc) + h * (F_ * U_) + u;

    float acc[8];
#pragma unroll
    for (int r = 0; r < 8; ++r) acc[r] = 0.f;

#pragma unroll 2
    for (int fc = 0; fc < 32; ++fc) {
        const float w0 = W[(4 * fc + 0) * U_];
        const float w1 = W[(4 * fc + 1) * U_];
        const float w2 = W[(4 * fc + 2) * U_];
        const float w3 = W[(4 * fc + 3) * U_];
#pragma unroll
        for (int r = 0; r < 8; ++r) {
            const float4 xv = xlds[r * 32 + fc];
            float s = acc[r];
            s = fmaf(xv.x, w0, s);
            s = fmaf(xv.y, w1, s);
            s = fmaf(xv.z, w2, s);
            s = fmaf(xv.w, w3, s);
            acc[r] = s;
        }
    }

    const float av = a[h * U_ + u];
    if (which == 1 && blockIdx.x == 0)
        ascaled[h * U_ + u] = (1.f - LEAKY_ALPHA) * av;

    const int b  = r0 >> 9;
    const int n0 = r0 & (N_ - 1);
    const int bh = b * H_ + h;

    if (which == 0) {
        short8 pk;
#pragma unroll
        for (int r = 0; r < 8; ++r) {
            const size_t base = ((size_t)(bh * N_ + n0 + r) << 5) + u;
            hsrc[base] = acc[r];
            pk[r] = f2bf_s(acc[r]);
        }
        *(short8*)&hsrcT[((size_t)(bh * U_) + u) * N_ + n0] = pk;
    } else {
        float4 v0, v1;
        v0.x = -acc[0]; v0.y = -acc[1]; v0.z = -acc[2]; v0.w = -acc[3];
        v1.x = -acc[4]; v1.y = -acc[5]; v1.z = -acc[6]; v1.w = -acc[7];
        float* dst = hdstNT + ((size_t)(bh * U_) + u) * N_ + n0;
        *(float4*)dst       = v0;
        *(float4*)(dst + 4) = v1;
#pragma unroll
        for (int r = 0; r < 8; ++r) {
            float v = acc[r] * av;
            v += __shfl_xor(v, 1);
            v += __shfl_xor(v, 2);
            v += __shfl_xor(v, 4);
            v += __shfl_xor(v, 8);
            v += __shfl_xor(v, 16);
            if (u == 0) Drow[bh * N_ + n0 + r] = v;
        }
    }
}

// ---------------------------------------------------------------------------
// Kernel 2: attention. Block = 512 thr = 8 waves; lane = j (owns one d-row,
// 32 PINNED named scalars, loaded coalesced from hdstNT). s-rows and a are
// block-uniform -> scalar loads (SGPR operands; R8's SGPR=112 proved the
// compiler scalarizes this). Phase A: zero LDS reads, zero shuffles; per i:
// 32 v_max + 32 v_fma + exp + one b16 p-write. l computed afterwards by an
// all-thread pbf reduce (2 b128 + 5 shfl per lane). Phase C: MFMA p @ srcT,
// B-frags direct from global hsrcT (proven R7 path).
// Grid = 32 bh x 32 tiles(16 i) = 1024 blocks.
// ---------------------------------------------------------------------------
__global__ __launch_bounds__(512, 4) void attn_kernel(
    const float* __restrict__ hsrc, const float* __restrict__ hdstNT,
    const float* __restrict__ Drow, const float* __restrict__ ascaled,
    const short* __restrict__ hsrcT, float* __restrict__ out)
{
    __shared__ __align__(16) short pbf[16 * PS];  // 16.6 KB p bf16 [i][j]
    __shared__ f32x4 scr[8][64];                  // 8 KB K-partials
    __shared__ float lfin[16];                    // 1/l per i

    const int t    = threadIdx.x;
    const int L    = t & 63;
    const int w    = __builtin_amdgcn_readfirstlane(t >> 6);
    const int tile = blockIdx.x & 31;
    const int bh   = blockIdx.x >> 5;
    const int h    = bh & 3;
    const int b    = bh >> 2;
    const size_t bhN = (size_t)bh * N_;
    const int ig0  = tile * 16;
    const int j    = t;                           // lane owns column j

    // ---- Phase A: per-lane d-row (coalesced, pinned) ----
    const float* dT = hdstNT + ((size_t)bh * U_) * N_ + j;
#define DL(k) float d##k = dT[(k) * N_];
    DL(0) DL(1) DL(2) DL(3) DL(4) DL(5) DL(6) DL(7)
    DL(8) DL(9) DL(10) DL(11) DL(12) DL(13) DL(14) DL(15)
    DL(16) DL(17) DL(18) DL(19) DL(20) DL(21) DL(22) DL(23)
    DL(24) DL(25) DL(26) DL(27) DL(28) DL(29) DL(30) DL(31)
#undef DL
    // Pin: sever the memory link so the compiler CANNOT re-load these.
#define PIN4(a0,a1,a2,a3) asm volatile("" : "+v"(a0), "+v"(a1), "+v"(a2), "+v"(a3));
    PIN4(d0,d1,d2,d3)     PIN4(d4,d5,d6,d7)
    PIN4(d8,d9,d10,d11)   PIN4(d12,d13,d14,d15)
    PIN4(d16,d17,d18,d19) PIN4(d20,d21,d22,d23)
    PIN4(d24,d25,d26,d27) PIN4(d28,d29,d30,d31)
#undef PIN4

    const float Dj = Drow[bhN + j];
    const float* sB = hsrc + ((bhN + ig0) << 5);  // 16x32, block-uniform
    const float* aS = ascaled + h * U_;           // block-uniform

#define TERM(k, dk, accv) accv = fmaf(aS[k], fmaxf(sR[k], dk), accv);
#pragma unroll 2
    for (int i = 0; i < 16; ++i) {
        const float* sR = sB + (i << 5);          // uniform -> s_load
        float acA = 0.f, acB = 0.f;
        TERM(0,  d0,  acA) TERM(1,  d1,  acB) TERM(2,  d2,  acA) TERM(3,  d3,  acB)
        TERM(4,  d4,  acA) TERM(5,  d5,  acB) TERM(6,  d6,  acA) TERM(7,  d7,  acB)
        TERM(8,  d8,  acA) TERM(9,  d9,  acB) TERM(10, d10, acA) TERM(11, d11, acB)
        TERM(12, d12, acA) TERM(13, d13, acB) TERM(14, d14, acA) TERM(15, d15, acB)
        TERM(16, d16, acA) TERM(17, d17, acB) TERM(18, d18, acA) TERM(19, d19, acB)
        TERM(20, d20, acA) TERM(21, d21, acB) TERM(22, d22, acA) TERM(23, d23, acB)
        TERM(24, d24, acA) TERM(25, d25, acB) TERM(26, d26, acA) TERM(27, d27, acB)
        TERM(28, d28, acA) TERM(29, d29, acB) TERM(30, d30, acA) TERM(31, d31, acB)
        const float e = __expf(Dj + acA + acB);
        pbf[i * PS + j] = f2bf_s(e);
    }
#undef TERM
    __syncthreads();

    // ---- l reduce: thread (ri = t>>5, rg = t&31) sums 16 j's of row ri ----
    {
        const int ri = t >> 5;
        const int rg = t & 31;
        const short8* pr = (const short8*)(pbf + ri * PS + rg * 16);
        const short8 pa = pr[0];
        const short8 pb = pr[1];
        float sum = 0.f;
#pragma unroll
        for (int k = 0; k < 8; ++k) sum += bf2f_s(pa[k]) + bf2f_s(pb[k]);
        sum += __shfl_xor(sum, 1);
        sum += __shfl_xor(sum, 2);
        sum += __shfl_xor(sum, 4);
        sum += __shfl_xor(sum, 8);
        sum += __shfl_xor(sum, 16);
        if (rg == 0) lfin[ri] = __builtin_amdgcn_rcpf(sum);
    }

    // ---- Phase C: MFMA  out = p @ src ; wave w = (nt = w&1, ks = w>>1) ----
    const int m  = L & 15;
    const int kq = L >> 4;
    const int nt = w & 1;
    const int ks = w >> 1;
    const short* Ap = pbf + m * PS + ks * 128 + kq * 8;
    const short* Bp = hsrcT + ((size_t)bh * U_ + nt * 16 + m) * N_ + ks * 128 + kq * 8;

    f32x4 acc = {0.f, 0.f, 0.f, 0.f};
#pragma unroll
    for (int st = 0; st < 4; ++st) {
        const short8 af = *(const short8*)(Ap + st * 32);
        const short8 bf = *(const short8*)(Bp + st * 32);
        acc = __builtin_amdgcn_mfma_f32_16x16x32_bf16(af, bf, acc, 0, 0, 0);
    }
    scr[w][L] = acc;
    __syncthreads();

    if (w < 2) {                               // wave w reduces ntile=w
        f32x4 s0 = scr[w][L];
        const f32x4 s1 = scr[w + 2][L];
        const f32x4 s2 = scr[w + 4][L];
        const f32x4 s3 = scr[w + 6][L];
        s0 += s1; s0 += s2; s0 += s3;
#pragma unroll
        for (int r = 0; r < 4; ++r) {
            const int il = kq * 4 + r;         // C/D: row=(lane>>4)*4+reg
            out[((size_t)(b * N_ + ig0 + il)) * (H_ * U_) + h * U_ + w * 16 + m]
                = s0[r] * lfin[il];
        }
    }
}

// ---------------------------------------------------------------------------
extern "C" void kernel_launch(void* const* d_in, const int* in_sizes, int n_in,
                              void* d_out, int out_size, void* d_ws, size_t ws_size,
                              hipStream_t stream) {
    const float* x    = (const float*)d_in[0];
    const float* Wsrc = (const float*)d_in[1];
    const float* Wdst = (const float*)d_in[2];
    const float* a    = (const float*)d_in[3];

    float* ws      = (float*)d_ws;
    float* hsrc    = ws;                                   // 524288 f
    float* hdstNT  = hsrc + (size_t)B_ * H_ * N_ * U_;     // 524288 f
    float* Drow    = hdstNT + (size_t)B_ * H_ * U_ * N_;   // 16384 f
    float* ascaled = Drow + (size_t)B_ * H_ * N_;          // 128 f
    short* hsrcT   = (short*)(ascaled + H_ * U_);          // 524288 sh

    proj_kernel<<<(B_ * N_) / 8, 256, 0, stream>>>(x, Wsrc, Wdst, a,
                                                   hsrc, hdstNT, Drow, ascaled,
                                                   hsrcT);
    attn_kernel<<<B_ * H_ * (N_ / 16), 512, 0, stream>>>(hsrc, hdstNT, Drow,
                                                         ascaled, hsrcT,
                                                         (float*)d_out);
}